// Round 1
// baseline (1344.438 us; speedup 1.0000x reference)
//
#include <hip/hip_runtime.h>

typedef _Float16 half8  __attribute__((ext_vector_type(8)));
typedef _Float16 half4_t __attribute__((ext_vector_type(4)));
typedef float    f32x4  __attribute__((ext_vector_type(4)));

__device__ __forceinline__ float gelu_exact(float x) {
  return 0.5f * x * (1.0f + erff(x * 0.70710678118654752f));
}

// ---------------- W [K][512] f32 -> Wt [512][K] f16 ----------------
__global__ __launch_bounds__(256)
void k_transpose_w(const float* __restrict__ W, _Float16* __restrict__ Wt, int K) {
  __shared__ float tile[32][33];
  int k0 = blockIdx.x * 32, n0 = blockIdx.y * 32, tid = threadIdx.x;
  int r = tid >> 3, c4 = (tid & 7) * 4;
  f32x4 v = *(const f32x4*)(W + (size_t)(k0 + r) * 512 + n0 + c4);
  tile[r][c4 + 0] = v[0]; tile[r][c4 + 1] = v[1];
  tile[r][c4 + 2] = v[2]; tile[r][c4 + 3] = v[3];
  __syncthreads();
  int rn = tid >> 3, ck = (tid & 7) * 4;
  half4_t o = { (_Float16)tile[ck + 0][rn], (_Float16)tile[ck + 1][rn],
                (_Float16)tile[ck + 2][rn], (_Float16)tile[ck + 3][rn] };
  *(half4_t*)(Wt + (size_t)(n0 + rn) * K + k0 + ck) = o;
}

// ---------------- basis [48][512] -> basisT [512][64] f16, zero-padded ----------------
__global__ __launch_bounds__(256)
void k_basis(const float* __restrict__ basis, _Float16* __restrict__ basisT) {
  int idx = blockIdx.x * 256 + threadIdx.x;   // 512*64 total
  int d = idx >> 6, m = idx & 63;
  float v = (m < 48) ? basis[(size_t)m * 512 + d] : 0.0f;
  basisT[idx] = (_Float16)v;
}

// ---------------- GEMM + bias + exact GELU -> f16 ----------------
// A logical [rows][Kdim] fp32 split at halfK between A0/A1 (feature concat).
// Wt [512][Kdim] f16 (pre-transposed). out [rows][512] f16.
__global__ __launch_bounds__(256)
void k_gemm_act(const float* __restrict__ A0, const float* __restrict__ A1,
                int halfK, int Kdim,
                const _Float16* __restrict__ Wt,
                const float* __restrict__ bias,
                _Float16* __restrict__ out) {
  // rows padded 32 -> 40 f16 (80B) to break ds_read_b128 bank aliasing
  __shared__ _Float16 As[128][40];
  __shared__ _Float16 Bs[128][40];
  const int tid = threadIdx.x;
  const int wave = tid >> 6, lane = tid & 63;
  const int l15 = lane & 15, q = lane >> 4;
  const int row0 = blockIdx.y * 128, col0 = blockIdx.x * 128;
  const int wm = (wave >> 1) * 64, wn = (wave & 1) * 64;
  const int a_r = tid >> 3, a_c = (tid & 7) * 4;     // A staging: 8 lanes/row
  const int b_n = tid >> 1, b_h = (tid & 1) * 16;    // B staging: 2 lanes/row

  f32x4 acc[4][4] = {};

  for (int k0 = 0; k0 < Kdim; k0 += 32) {
    const float* Ap = (k0 < halfK) ? A0 : A1;
    int kloc = (k0 < halfK) ? k0 : k0 - halfK;
    __syncthreads();
#pragma unroll
    for (int j = 0; j < 4; ++j) {
      int r = a_r + j * 32;
      f32x4 v = *(const f32x4*)(Ap + (size_t)(row0 + r) * halfK + kloc + a_c);
      half4_t h = { (_Float16)v[0], (_Float16)v[1], (_Float16)v[2], (_Float16)v[3] };
      *(half4_t*)&As[r][a_c] = h;
    }
    {
      const half8* bsrc = (const half8*)(Wt + (size_t)(col0 + b_n) * Kdim + k0 + b_h);
      half8 w0 = bsrc[0];
      half8 w1 = bsrc[1];
      *(half8*)&Bs[b_n][b_h + 0] = w0;
      *(half8*)&Bs[b_n][b_h + 8] = w1;
    }
    __syncthreads();
    half8 af[4], bf[4];
#pragma unroll
    for (int mt = 0; mt < 4; ++mt) af[mt] = *(const half8*)&As[wm + mt * 16 + l15][q * 8];
#pragma unroll
    for (int nt = 0; nt < 4; ++nt) bf[nt] = *(const half8*)&Bs[wn + nt * 16 + l15][q * 8];
#pragma unroll
    for (int mt = 0; mt < 4; ++mt)
#pragma unroll
      for (int nt = 0; nt < 4; ++nt)
        acc[mt][nt] = __builtin_amdgcn_mfma_f32_16x16x32_f16(af[mt], bf[nt], acc[mt][nt], 0, 0, 0);
  }

#pragma unroll
  for (int mt = 0; mt < 4; ++mt) {
    int rbase = row0 + wm + mt * 16 + q * 4;
#pragma unroll
    for (int nt = 0; nt < 4; ++nt) {
      int c = col0 + wn + nt * 16 + l15;
      float bz = bias[c];
#pragma unroll
      for (int r = 0; r < 4; ++r) {
        float x = acc[mt][nt][r] + bz;
        out[(size_t)(rbase + r) * 512 + c] = (_Float16)gelu_exact(x);
      }
    }
  }
}

// ---------------- in-place LayerNorm over D=512, one wave per row ----------------
__global__ __launch_bounds__(256)
void k_layernorm(_Float16* __restrict__ qact, _Float16* __restrict__ kact,
                 const float* __restrict__ gq, const float* __restrict__ betaq,
                 const float* __restrict__ gk, const float* __restrict__ betak) {
  int wid = blockIdx.x * 4 + (threadIdx.x >> 6);
  int lane = threadIdx.x & 63;
  _Float16* base; const float *g, *be;
  if (wid < 16384) { base = qact + (size_t)wid * 512;           g = gq; be = betaq; }
  else             { base = kact + (size_t)(wid - 16384) * 512; g = gk; be = betak; }
  half4_t x0 = *(const half4_t*)(base + lane * 4);
  half4_t x1 = *(const half4_t*)(base + 256 + lane * 4);
  float xs[8];
#pragma unroll
  for (int i = 0; i < 4; ++i) { xs[i] = (float)x0[i]; xs[4 + i] = (float)x1[i]; }
  float s = 0.f;
#pragma unroll
  for (int i = 0; i < 8; ++i) s += xs[i];
#pragma unroll
  for (int m = 1; m < 64; m <<= 1) s += __shfl_xor(s, m, 64);
  float mu = s * (1.0f / 512.0f);
  float vv = 0.f;
#pragma unroll
  for (int i = 0; i < 8; ++i) { float d = xs[i] - mu; vv += d * d; }
#pragma unroll
  for (int m = 1; m < 64; m <<= 1) vv += __shfl_xor(vv, m, 64);
  float rs = rsqrtf(vv * (1.0f / 512.0f) + 1e-5f);
  f32x4 g0 = *(const f32x4*)(g + lane * 4);
  f32x4 g1 = *(const f32x4*)(g + 256 + lane * 4);
  f32x4 b0 = *(const f32x4*)(be + lane * 4);
  f32x4 b1 = *(const f32x4*)(be + 256 + lane * 4);
  half4_t y0, y1;
#pragma unroll
  for (int i = 0; i < 4; ++i) {
    y0[i] = (_Float16)((xs[i]     - mu) * rs * g0[i] + b0[i]);
    y1[i] = (_Float16)((xs[4 + i] - mu) * rs * g1[i] + b1[i]);
  }
  *(half4_t*)(base + lane * 4) = y0;
  *(half4_t*)(base + 256 + lane * 4) = y1;
}

// ---------------- attention: one wave per batch ----------------
// scores = q@k^T*scale + depth_bias ; softmax ; z = alpha@basis
__global__ __launch_bounds__(256)
void k_attn(const _Float16* __restrict__ qh, const _Float16* __restrict__ kh,
            const _Float16* __restrict__ basisT,
            float* __restrict__ z, float* __restrict__ alpha_out) {
  __shared__ _Float16 P[4][32][72];   // per-wave P (32 l x 64 m padded), +8 pad vs 64 for banks
  const int wave = threadIdx.x >> 6, lane = threadIdx.x & 63;
  const int l15 = lane & 15, q = lane >> 4;
  const int b = blockIdx.x * 4 + wave;
  const _Float16* qb = qh + (size_t)b * 32 * 512;
  const _Float16* kb = kh + (size_t)b * 48 * 512;

  f32x4 sacc[2][3] = {};
#pragma unroll 4
  for (int ks = 0; ks < 16; ++ks) {
    int ko = ks * 32 + q * 8;
    half8 af0 = *(const half8*)(qb + (size_t)(l15)      * 512 + ko);
    half8 af1 = *(const half8*)(qb + (size_t)(16 + l15) * 512 + ko);
    half8 bf0 = *(const half8*)(kb + (size_t)(l15)      * 512 + ko);
    half8 bf1 = *(const half8*)(kb + (size_t)(16 + l15) * 512 + ko);
    half8 bf2 = *(const half8*)(kb + (size_t)(32 + l15) * 512 + ko);
    sacc[0][0] = __builtin_amdgcn_mfma_f32_16x16x32_f16(af0, bf0, sacc[0][0], 0, 0, 0);
    sacc[0][1] = __builtin_amdgcn_mfma_f32_16x16x32_f16(af0, bf1, sacc[0][1], 0, 0, 0);
    sacc[0][2] = __builtin_amdgcn_mfma_f32_16x16x32_f16(af0, bf2, sacc[0][2], 0, 0, 0);
    sacc[1][0] = __builtin_amdgcn_mfma_f32_16x16x32_f16(af1, bf0, sacc[1][0], 0, 0, 0);
    sacc[1][1] = __builtin_amdgcn_mfma_f32_16x16x32_f16(af1, bf1, sacc[1][1], 0, 0, 0);
    sacc[1][2] = __builtin_amdgcn_mfma_f32_16x16x32_f16(af1, bf2, sacc[1][2], 0, 0, 0);
  }

  const float scale = 0.04419417382415922f;   // 1/sqrt(512)
#pragma unroll
  for (int lt = 0; lt < 2; ++lt) {
#pragma unroll
    for (int r = 0; r < 4; ++r) {
      int l = lt * 16 + q * 4 + r;
      float li = (float)l * (1.0f / 31.0f);
      float s0 = sacc[lt][0][r] * scale - fabsf(li - (float)(l15)      * (1.0f / 47.0f));
      float s1 = sacc[lt][1][r] * scale - fabsf(li - (float)(l15 + 16) * (1.0f / 47.0f));
      float s2 = sacc[lt][2][r] * scale - fabsf(li - (float)(l15 + 32) * (1.0f / 47.0f));
      float mx = fmaxf(s0, fmaxf(s1, s2));
#pragma unroll
      for (int m = 1; m < 16; m <<= 1) mx = fmaxf(mx, __shfl_xor(mx, m, 16));
      float e0 = __expf(s0 - mx), e1 = __expf(s1 - mx), e2 = __expf(s2 - mx);
      float sm = e0 + e1 + e2;
#pragma unroll
      for (int m = 1; m < 16; m <<= 1) sm += __shfl_xor(sm, m, 16);
      float inv = 1.0f / sm;
      e0 *= inv; e1 *= inv; e2 *= inv;
      float* ao = alpha_out + ((size_t)b * 32 + l) * 48 + l15;
      ao[0] = e0; ao[16] = e1; ao[32] = e2;
      P[wave][l][l15]      = (_Float16)e0;
      P[wave][l][l15 + 16] = (_Float16)e1;
      P[wave][l][l15 + 32] = (_Float16)e2;
    }
  }
  { // zero-pad m = 48..63 (K padding for the z-GEMM)
    half8 zz = {};
    *(half8*)&P[wave][lane >> 1][48 + (lane & 1) * 8] = zz;
  }
  __syncthreads();

  half8 pf[2][2];
#pragma unroll
  for (int lt = 0; lt < 2; ++lt)
#pragma unroll
    for (int ks = 0; ks < 2; ++ks)
      pf[lt][ks] = *(const half8*)&P[wave][lt * 16 + l15][ks * 32 + q * 8];

#pragma unroll
  for (int nc = 0; nc < 4; ++nc) {
    f32x4 zacc[2][8] = {};
#pragma unroll
    for (int nt = 0; nt < 8; ++nt) {
      int d = (nc * 8 + nt) * 16 + l15;
#pragma unroll
      for (int ks = 0; ks < 2; ++ks) {
        half8 bfr = *(const half8*)(basisT + (size_t)d * 64 + ks * 32 + q * 8);
        zacc[0][nt] = __builtin_amdgcn_mfma_f32_16x16x32_f16(pf[0][ks], bfr, zacc[0][nt], 0, 0, 0);
        zacc[1][nt] = __builtin_amdgcn_mfma_f32_16x16x32_f16(pf[1][ks], bfr, zacc[1][nt], 0, 0, 0);
      }
    }
#pragma unroll
    for (int lt = 0; lt < 2; ++lt)
#pragma unroll
      for (int nt = 0; nt < 8; ++nt) {
        int dd = (nc * 8 + nt) * 16 + l15;
#pragma unroll
        for (int r = 0; r < 4; ++r)
          z[((size_t)b * 32 + lt * 16 + q * 4 + r) * 512 + dd] = zacc[lt][nt][r];
      }
  }
}

extern "C" void kernel_launch(void* const* d_in, const int* in_sizes, int n_in,
                              void* d_out, int out_size, void* d_ws, size_t ws_size,
                              hipStream_t stream) {
  const float* student_o = (const float*)d_in[0];
  const float* student_d = (const float*)d_in[1];
  const float* teacher_o = (const float*)d_in[2];
  const float* teacher_d = (const float*)d_in[3];
  const float* Wq    = (const float*)d_in[4];
  const float* bq    = (const float*)d_in[5];
  const float* gq    = (const float*)d_in[6];
  const float* betaq = (const float*)d_in[7];
  const float* Wk    = (const float*)d_in[8];
  const float* bk    = (const float*)d_in[9];
  const float* gk    = (const float*)d_in[10];
  const float* betak = (const float*)d_in[11];
  const float* basis = (const float*)d_in[12];

  char* ws = (char*)d_ws;
  _Float16* WqT    = (_Float16*)(ws);                       // 512*2048*2 = 2,097,152
  _Float16* WkT    = (_Float16*)(ws + 2097152);             // 512*8192*2 = 8,388,608
  _Float16* basisT = (_Float16*)(ws + 10485760);            // 512*64*2   =    65,536
  _Float16* qact   = (_Float16*)(ws + 10551296);            // 16384*512*2 = 16,777,216
  _Float16* kact   = (_Float16*)(ws + 27328512);            // 24576*512*2 = 25,165,824
  // total ws used: 52,494,336 bytes

  float* out_z     = (float*)d_out;                         // [512,32,512]
  float* out_alpha = out_z + (size_t)512 * 32 * 512;        // [512,32,48]

  k_transpose_w<<<dim3(64, 16),  256, 0, stream>>>(Wq, WqT, 2048);
  k_transpose_w<<<dim3(256, 16), 256, 0, stream>>>(Wk, WkT, 8192);
  k_basis<<<128, 256, 0, stream>>>(basis, basisT);
  // grid.x = N-blocks (fastest-varying) so the 4 column-blocks sharing an A
  // row-slice dispatch back-to-back -> L3 absorbs the A re-read.
  k_gemm_act<<<dim3(4, 128), 256, 0, stream>>>(student_o, student_d, 1024, 2048, WqT, bq, qact);
  k_gemm_act<<<dim3(4, 192), 256, 0, stream>>>(teacher_o, teacher_d, 4096, 8192, WkT, bk, kact);
  k_layernorm<<<10240, 256, 0, stream>>>(qact, kact, gq, betaq, gk, betak);
  k_attn<<<128, 256, 0, stream>>>(qact, kact, basisT, out_z, out_alpha);
}